// Round 6
// baseline (278.922 us; speedup 1.0000x reference)
//
#include <hip/hip_runtime.h>
#include <cstdint>
#include <cstddef>

#define GLOBAL_AS __attribute__((address_space(1)))
#define LDS_AS __attribute__((address_space(3)))

typedef __attribute__((ext_vector_type(8))) short short8;
typedef __attribute__((ext_vector_type(4))) float floatx4;
typedef __attribute__((ext_vector_type(2))) long long2v;   // 16B LDS read
typedef __attribute__((ext_vector_type(4))) int int4v;
typedef __attribute__((ext_vector_type(8))) int int8v;

#if defined(__has_builtin)
#if __has_builtin(__builtin_amdgcn_cvt_pk_fp8_f32)
#define HAVE_HW_FP8 1
#endif
#endif

static __device__ __forceinline__ unsigned short f2bf(float f) {
  uint32_t u = __builtin_bit_cast(uint32_t, f);
  u += 0x7fffu + ((u >> 16) & 1u);
  return (unsigned short)(u >> 16);
}

// OCP e4m3 encode (RNE, saturate to 448)
static __device__ __forceinline__ unsigned char f2fp8(float f) {
#ifdef HAVE_HW_FP8
  float c = fminf(fmaxf(f, -448.f), 448.f);
  return (unsigned char)(__builtin_amdgcn_cvt_pk_fp8_f32(c, 0.f, 0, false) & 0xff);
#else
  unsigned char s = 0;
  if (f < 0.f) { s = 0x80; f = -f; }
  if (f >= 448.f) return s | 0x7e;
  if (f < 0.015625f) { int r = (int)(f * 512.f + 0.5f); return s | (unsigned char)r; }
  uint32_t u = __builtin_bit_cast(uint32_t, f);
  int e = (int)((u >> 23) & 0xff) - 127;
  uint32_t keep = (u >> 20) & 7, rest = u & 0xfffffu;
  if (rest > 0x80000u || (rest == 0x80000u && (keep & 1))) ++keep;
  if (keep == 8) { keep = 0; ++e; }
  if (e > 8) return s | 0x7e;
  return s | (unsigned char)(((e + 7) << 3) | keep);
#endif
}

// pack 4 fp8 bytes (cols l15+{0,16,32,48}) into one dword, bytes in j order
static __device__ __forceinline__ uint32_t pack4fp8(const float e[4]) {
#ifdef HAVE_HW_FP8
  const uint32_t p01 = (uint32_t)__builtin_amdgcn_cvt_pk_fp8_f32(e[0], e[1], 0, false);
  const uint32_t p23 = (uint32_t)__builtin_amdgcn_cvt_pk_fp8_f32(e[2], e[3], 0, false);
  return (p01 & 0xffffu) | (p23 << 16);
#else
  return (uint32_t)f2fp8(e[0]) | ((uint32_t)f2fp8(e[1]) << 8) |
         ((uint32_t)f2fp8(e[2]) << 16) | ((uint32_t)f2fp8(e[3]) << 24);
#endif
}

// ---------------------------------------------------------------------------
// FP8 STORAGE PERMUTATION (both-sides trick): every fp8 tensor stores, within
// each 64-byte column group, original col c at byte s = 4*(c&15) + (c>>4)
// (16x16 MFMA C-fragment-native). Consumers apply the same k-permutation to
// A and B -> dot products unchanged.
// ---------------------------------------------------------------------------

static __device__ __forceinline__ void wait_vm0() {
  __builtin_amdgcn_s_waitcnt(0x0f70);  // vmcnt(0)
}
static __device__ __forceinline__ void wait_vm4() {
  __builtin_amdgcn_s_waitcnt(0x0f74);  // vmcnt(4)
}
static __device__ __forceinline__ void sfence() {
  __builtin_amdgcn_sched_barrier(0);
}
static __device__ __forceinline__ void phase_bar() {
  sfence();
  __builtin_amdgcn_s_barrier();
  sfence();
}

// ---------------------------------------------------------------------------
// MX helpers (pv8 only): BK=128 fp8. LDS row = 128 B (8 chunks of 16 B);
// chunk c of row r stored at r*128 + ((c ^ (r&7))*16) — conflict-free b128.
// scale E8M0=127 (=1.0) -> arithmetic identical to non-scaled e4m3.
// ---------------------------------------------------------------------------
static __device__ __forceinline__ int8v load_frag32(const unsigned char* base, int row, int quad) {
  const int h = row & 7;
  const int c0 = (2 * quad) ^ h;
  const int c1 = (2 * quad + 1) ^ h;
  const int4v lo = *(const int4v*)(base + row * 128 + c0 * 16);
  const int4v hi = *(const int4v*)(base + row * 128 + c1 * 16);
  int8v r;
  r[0] = lo[0]; r[1] = lo[1]; r[2] = lo[2]; r[3] = lo[3];
  r[4] = hi[0]; r[5] = hi[1]; r[6] = hi[2]; r[7] = hi[3];
  return r;
}

static __device__ __forceinline__ floatx4 mx_mfma(int8v a, int8v b, floatx4 c) {
  return __builtin_amdgcn_mfma_scale_f32_16x16x128_f8f6f4(a, b, c, 0, 0, 0, 0x7f, 0, 0x7f);
}

// ---------------------------------------------------------------------------
// Transpose H: fp32 [R][C] -> HbT8 fp8 [C][R] (R permuted sigma1 within
// 64-groups to match P8's col permutation), plus straight bf16 copy [R][C],
// plus residual prefill out = H (pv8 atomically accumulates on top).
// ---------------------------------------------------------------------------
__global__ __launch_bounds__(256) void transpose_h_kernel(
    const float* __restrict__ in, unsigned char* __restrict__ outT8,
    unsigned short* __restrict__ outN, float* __restrict__ outF,
    int R, int C) {
  __shared__ float t[64][65];
  const int bc = blockIdx.x * 64;
  const int br = blockIdx.y * 64;
  const int tc = threadIdx.x & 63;
  const int tr = threadIdx.x >> 6;
  for (int r = tr; r < 64; r += 4) {
    const float v = in[(size_t)(br + r) * C + bc + tc];
    t[r][tc] = v;
    outN[(size_t)(br + r) * C + bc + tc] = f2bf(v);
    outF[(size_t)(br + r) * C + bc + tc] = v;   // residual prefill
  }
  __syncthreads();
  const int tperm = 4 * (tc & 15) + (tc >> 4);   // sigma1: match P8 col perm
  for (int r = tr; r < 64; r += 4)
    outT8[(size_t)(bc + r) * R + br + tperm] = f2fp8(t[tc][r]);
}

// Transpose both weights: fp32 [D][D] -> bf16 [D][D]^T, z selects Wq/Wk
__global__ __launch_bounds__(256) void transpose_w2_kernel(
    const float* __restrict__ Wq, const float* __restrict__ Wk,
    unsigned short* __restrict__ outT, int Dd) {
  const float* in = blockIdx.z ? Wk : Wq;
  unsigned short* out = outT + (size_t)blockIdx.z * Dd * Dd;
  __shared__ float t[64][65];
  const int bc = blockIdx.x * 64;
  const int br = blockIdx.y * 64;
  const int tc = threadIdx.x & 63;
  const int tr = threadIdx.x >> 6;
  for (int r = tr; r < 64; r += 4)
    t[r][tc] = in[(size_t)(br + r) * Dd + bc + tc];
  __syncthreads();
  for (int r = tr; r < 64; r += 4)
    out[(size_t)(bc + r) * Dd + br + tc] = f2bf(t[tc][r]);
}

__global__ __launch_bounds__(256) void pack_bias_kernel(
    const float* __restrict__ bq, const float* __restrict__ bk,
    float* __restrict__ bqk) {
  int i = blockIdx.x * 256 + threadIdx.x;
  bqk[i] = (i < 512) ? bq[i] : bk[i - 512];
}

// ---------------------------------------------------------------------------
// Projection GEMM (bf16 x bf16 -> fp8): QK8[m][p(n)] = fp8(A[m][k]*Bt[n][k]+b[n])
// 128x128 tile, BK=32, double-buffered one-barrier K-loop. Output sigma1.
// ---------------------------------------------------------------------------
__global__ __launch_bounds__(256, 4) void gemm_proj(
    const unsigned short* __restrict__ A,    // Hb [8192][512] bf16
    const unsigned short* __restrict__ Bt,   // BqkT [1024][512] bf16
    int Ncols, int K,
    const float* __restrict__ bias,
    unsigned char* __restrict__ C8)          // QK8 [8192][1024] fp8 (sigma1 cols)
{
  __shared__ unsigned short As[2][128 * 32];
  __shared__ unsigned short Bs[2][128 * 32];

  const int tid  = threadIdx.x;
  const int lane = tid & 63;
  const int wave = tid >> 6;
  const int wr   = (wave >> 1) * 64;
  const int wc   = (wave & 1) * 64;
  const int quad = lane >> 4;
  const int l15  = lane & 15;
  const int bm   = blockIdx.y * 128;
  const int bn   = blockIdx.x * 128;

  const int c0 = tid, c1 = tid + 256;
  const int r0a = c0 >> 2, k0a = (((c0 & 3) ^ ((c0 >> 3) & 3)) << 3);
  const int r1a = c1 >> 2, k1a = (((c1 & 3) ^ ((c1 >> 3) & 3)) << 3);

  auto stage = [&](int kt, int b) {
    __builtin_amdgcn_global_load_lds(
        (const GLOBAL_AS void*)(A + (size_t)(bm + r0a) * K + kt + k0a),
        (LDS_AS void*)(&As[b][c0 * 8]), 16, 0, 0);
    __builtin_amdgcn_global_load_lds(
        (const GLOBAL_AS void*)(A + (size_t)(bm + r1a) * K + kt + k1a),
        (LDS_AS void*)(&As[b][c1 * 8]), 16, 0, 0);
    __builtin_amdgcn_global_load_lds(
        (const GLOBAL_AS void*)(Bt + (size_t)(bn + r0a) * K + kt + k0a),
        (LDS_AS void*)(&Bs[b][c0 * 8]), 16, 0, 0);
    __builtin_amdgcn_global_load_lds(
        (const GLOBAL_AS void*)(Bt + (size_t)(bn + r1a) * K + kt + k1a),
        (LDS_AS void*)(&Bs[b][c1 * 8]), 16, 0, 0);
  };

  floatx4 acc[4][4];
#pragma unroll
  for (int i = 0; i < 4; ++i)
#pragma unroll
    for (int j = 0; j < 4; ++j)
      acc[i][j] = (floatx4){0.f, 0.f, 0.f, 0.f};

  stage(0, 0);
  const int swq = quad ^ ((l15 >> 1) & 3);   // un-swizzle: orig chunk `quad`
  const int nIter = K >> 5;
  for (int it = 0; it < nIter; ++it) {
    const int b = it & 1;
    wait_vm0();
    __syncthreads();
    if (it + 1 < nIter) stage((it + 1) << 5, b ^ 1);

    short8 af[4], bfr[4];
#pragma unroll
    for (int i = 0; i < 4; ++i)
      af[i] = *(const short8*)(&As[b][(wr + i * 16 + l15) * 32 + swq * 8]);
#pragma unroll
    for (int j = 0; j < 4; ++j)
      bfr[j] = *(const short8*)(&Bs[b][(wc + j * 16 + l15) * 32 + swq * 8]);
#pragma unroll
    for (int i = 0; i < 4; ++i)
#pragma unroll
      for (int j = 0; j < 4; ++j)
        acc[i][j] = __builtin_amdgcn_mfma_f32_16x16x32_bf16(af[i], bfr[j], acc[i][j], 0, 0, 0);
  }

  // epilogue — C/D layout: col = lane&15, row = quad*4 + reg. sigma1 store.
#pragma unroll
  for (int i = 0; i < 4; ++i) {
    const int rl = bm + wr + i * 16 + quad * 4;
#pragma unroll
    for (int r = 0; r < 4; ++r) {
      const int row = rl + r;
      float e[4];
#pragma unroll
      for (int j = 0; j < 4; ++j)
        e[j] = acc[i][j][r] + bias[bn + wc + j * 16 + l15];
      const uint32_t d = pack4fp8(e);
      *(uint32_t*)(C8 + (size_t)row * Ncols + bn + wc + 4 * l15) = d;
    }
  }
}

// ---------------------------------------------------------------------------
// Scores GEMM fp8 x fp8 — 256x256 8-phase schedule (m201-template port):
// 512 threads = 8 waves (2m x 4n), per-wave output 128x64, acc[8][4].
// BK=64, THREE LDS buffers (96 KiB), tile t+2 staged during iter t into
// buf (t+2)%3 (never the buffer being read). Counted vmcnt: iter entry
// waits vmcnt(4) (tile t landed, t+1 in flight; ~2-iter lead), vmcnt(0)
// only at the last tile. 4 phases/tile, each
// {ds_read subtile || stage half-tile -> s_barrier -> setprio(1) ->
//  16 MFMA quadrant -> setprio(0) -> s_barrier}, sched_barrier(0)-pinned.
// Staging/read swizzle + sigma1 epilogue identical to the proven 128² kernel.
// ---------------------------------------------------------------------------
__global__ __launch_bounds__(512, 1) void gemm_qk8(
    const unsigned char* __restrict__ A,     // Q8 rows [.][lda] fp8
    const unsigned char* __restrict__ Bt,    // K8 [8192][ldb] fp8
    int Ncols, int K, int lda, int ldb,
    float* __restrict__ lsum,
    int row0,
    unsigned char* __restrict__ P8)
{
  __shared__ unsigned char AsB[3][256 * 64];  // 16 KiB x3
  __shared__ unsigned char BsB[3][256 * 64];  // 16 KiB x3

  const int tid  = threadIdx.x;
  const int lane = tid & 63;
  const int wave = tid >> 6;     // 0..7
  const int wm   = wave >> 2;    // 0..1  (m-half of block rows)
  const int wn   = wave & 3;     // 0..3  (n-quarter of block cols)
  const int quad = lane >> 4;
  const int l15  = lane & 15;

  int bxn = blockIdx.x, byn = blockIdx.y;
  if (gridDim.x == 32 && gridDim.y == 32) {
    // XCD region swizzle: each XCD owns an 8(bn) x 16(bm) region (bijective)
    const int id = blockIdx.y * 32 + blockIdx.x;
    const int r = id & 7, w = id >> 3;
    bxn = (r & 3) * 8 + (w & 7);
    byn = (r >> 2) * 16 + (w >> 3);
  }
  const int bm = byn * 256;
  const int bn = bxn * 256;

  // staging: half-tile h = rows [h*128,h*128+128) of BOTH A and B.
  // per thread: 1 A-chunk + 1 B-chunk of 16 B (512 thr x 16 B = 8 KB = half).
  const int srow128 = tid >> 2;          // 0..127
  const int schunk  = tid & 3;
  auto stage_h = [&](int kt, unsigned char* la, unsigned char* lb, int h) {
    const int row  = h * 128 + srow128;
    const int gcol = ((schunk ^ ((row >> 1) & 3)) << 4);   // pre-swizzled src
    __builtin_amdgcn_global_load_lds(
        (const GLOBAL_AS void*)(A + (size_t)(bm + row) * lda + kt + gcol),
        (LDS_AS void*)(la + row * 64 + schunk * 16), 16, 0, 0);
    __builtin_amdgcn_global_load_lds(
        (const GLOBAL_AS void*)(Bt + (size_t)(bn + row) * ldb + kt + gcol),
        (LDS_AS void*)(lb + row * 64 + schunk * 16), 16, 0, 0);
  };

  floatx4 acc[8][4];
#pragma unroll
  for (int i = 0; i < 8; ++i)
#pragma unroll
    for (int j = 0; j < 4; ++j)
      acc[i][j] = (floatx4){0.f, 0.f, 0.f, 0.f};

  unsigned char *a0 = AsB[0], *a1 = AsB[1], *a2 = AsB[2];
  unsigned char *b0 = BsB[0], *b1 = BsB[1], *b2 = BsB[2];

  // prologue: tiles 0 and 1 fully staged (8 loads/thread outstanding)
  stage_h(0, a0, b0, 0);  stage_h(0, a0, b0, 1);
  stage_h(64, a1, b1, 0); stage_h(64, a1, b1, 1);

  const int swq = quad ^ ((l15 >> 1) & 3);   // un-swizzle: orig chunk `quad`
  const int nT = K >> 6;                     // 8 tiles

  long2v aF[4], bF0[2], bF1[2];

  for (int t = 0; t < nT; ++t) {
    // entry: tile t landed for THIS wave, then barrier -> landed for ALL
    if (t + 1 < nT) wait_vm4(); else wait_vm0();
    phase_bar();

    const unsigned char* ca = a0;
    const unsigned char* cb = b0;
    const bool pf  = (t + 2 < nT);
    const int  kt2 = (t + 2) << 6;

    // ---- phase 0: read A(mh0) + B(nh0); stage half0 of t+2; MFMA q(0,0)
#pragma unroll
    for (int ii = 0; ii < 4; ++ii)
      aF[ii] = *(const long2v*)(ca + (wm * 128 + ii * 16 + l15) * 64 + swq * 16);
#pragma unroll
    for (int jj = 0; jj < 2; ++jj)
      bF0[jj] = *(const long2v*)(cb + (wn * 64 + jj * 16 + l15) * 64 + swq * 16);
    if (pf) stage_h(kt2, a2, b2, 0);
    phase_bar();
    __builtin_amdgcn_s_setprio(1);
#pragma unroll
    for (int ii = 0; ii < 4; ++ii)
#pragma unroll
      for (int jj = 0; jj < 2; ++jj) {
        acc[ii][jj] = __builtin_amdgcn_mfma_f32_16x16x32_fp8_fp8(aF[ii].x, bF0[jj].x, acc[ii][jj], 0, 0, 0);
        acc[ii][jj] = __builtin_amdgcn_mfma_f32_16x16x32_fp8_fp8(aF[ii].y, bF0[jj].y, acc[ii][jj], 0, 0, 0);
      }
    __builtin_amdgcn_s_setprio(0);
    phase_bar();

    // ---- phase 1: read B(nh1); stage half1 of t+2; MFMA q(0,1)
#pragma unroll
    for (int jj = 0; jj < 2; ++jj)
      bF1[jj] = *(const long2v*)(cb + (wn * 64 + 32 + jj * 16 + l15) * 64 + swq * 16);
    if (pf) stage_h(kt2, a2, b2, 1);
    phase_bar();
    __builtin_amdgcn_s_setprio(1);
#pragma unroll
    for (int ii = 0; ii < 4; ++ii)
#pragma unroll
      for (int jj = 0; jj < 2; ++jj) {
        acc[ii][2 + jj] = __builtin_amdgcn_mfma_f32_16x16x32_fp8_fp8(aF[ii].x, bF1[jj].x, acc[ii][2 + jj], 0, 0, 0);
        acc[ii][2 + jj] = __builtin_amdgcn_mfma_f32_16x16x32_fp8_fp8(aF[ii].y, bF1[jj].y, acc[ii][2 + jj], 0, 0, 0);
      }
    __builtin_amdgcn_s_setprio(0);
    phase_bar();

    // ---- phase 2: read A(mh1); MFMA q(1,1)
#pragma unroll
    for (int ii = 0; ii < 4; ++ii)
      aF[ii] = *(const long2v*)(ca + (wm * 128 + 64 + ii * 16 + l15) * 64 + swq * 16);
    phase_bar();
    __builtin_amdgcn_s_setprio(1);
#pragma unroll
    for (int ii = 0; ii < 4; ++ii)
#pragma unroll
      for (int jj = 0; jj < 2; ++jj) {
        acc[4 + ii][2 + jj] = __builtin_amdgcn_mfma_f32_16x16x32_fp8_fp8(aF[ii].x, bF1[jj].x, acc[4 + ii][2 + jj], 0, 0, 0);
        acc[4 + ii][2 + jj] = __builtin_amdgcn_mfma_f32_16x16x32_fp8_fp8(aF[ii].y, bF1[jj].y, acc[4 + ii][2 + jj], 0, 0, 0);
      }
    __builtin_amdgcn_s_setprio(0);
    phase_bar();

    // ---- phase 3: MFMA q(1,0) (reuses aF(mh1) + bF0; no new reads)
    __builtin_amdgcn_s_setprio(1);
#pragma unroll
    for (int ii = 0; ii < 4; ++ii)
#pragma unroll
      for (int jj = 0; jj < 2; ++jj) {
        acc[4 + ii][jj] = __builtin_amdgcn_mfma_f32_16x16x32_fp8_fp8(aF[ii].x, bF0[jj].x, acc[4 + ii][jj], 0, 0, 0);
        acc[4 + ii][jj] = __builtin_amdgcn_mfma_f32_16x16x32_fp8_fp8(aF[ii].y, bF0[jj].y, acc[4 + ii][jj], 0, 0, 0);
      }
    __builtin_amdgcn_s_setprio(0);

    // rotate buffers: cur <- next1 <- next2 <- cur
    unsigned char* ta = a0; a0 = a1; a1 = a2; a2 = ta;
    unsigned char* tb = b0; b0 = b1; b1 = b2; b2 = tb;
  }

  // epilogue — per 16x16 frag: col = lane&15, row = quad*4 + reg. sigma1.
  const float scale = 0.044194173824159216f;  // 1/sqrt(512)
#pragma unroll
  for (int i = 0; i < 8; ++i) {
    const int rl = bm + wm * 128 + i * 16 + quad * 4;
#pragma unroll
    for (int r = 0; r < 4; ++r) {
      const int row = rl + r;
      float e4[4];
#pragma unroll
      for (int j = 0; j < 4; ++j) {
        const int col = bn + wn * 64 + j * 16 + l15;
        const float lg = ((row0 + row) == col) ? 0.f : acc[i][j][r] * scale;
        e4[j] = fminf(__expf(lg), 448.f);
      }
      float rsum = (e4[0] + e4[1]) + (e4[2] + e4[3]);
      const uint32_t d = pack4fp8(e4);   // fragment-native store, no gather
      *(uint32_t*)(P8 + (size_t)row * Ncols + bn + wn * 64 + 4 * l15) = d;
      rsum += __shfl_xor(rsum, 1);
      rsum += __shfl_xor(rsum, 2);
      rsum += __shfl_xor(rsum, 4);
      rsum += __shfl_xor(rsum, 8);
      if (l15 == 0) atomicAdd(&lsum[row0 + row], rsum);
    }
  }
}

// ---------------------------------------------------------------------------
// PV GEMM, MX fp8: out[m][n] += (sum_k P8[m][k]*HbT8[n][k]) / l[m].
// Shared k-dim identically sigma1-permuted in P8 and HbT8 -> dot unchanged.
// 64x128 tile, BK=128, double-buffered, split-K over z accumulating with
// device-scope fp32 atomics into out (pre-filled with residual H).
// XCD swizzle: the 4 d-blocks sharing one 64-row P8 panel on one XCD's L2.
// ---------------------------------------------------------------------------
__global__ __launch_bounds__(256, 3) void gemm_pv8(
    const unsigned char* __restrict__ P,     // [rows][8192] fp8 (chunk base)
    const unsigned char* __restrict__ Bt,    // HbT8 [512][8192] fp8
    int Kchunk,
    const float* __restrict__ lvec,
    int row0,
    float* __restrict__ out)
{
  __shared__ unsigned char As[2][64 * 128];   // 8 KiB x2
  __shared__ unsigned char Bs[2][128 * 128];  // 16 KiB x2

  const int tid  = threadIdx.x;
  const int lane = tid & 63;
  const int wave = tid >> 6;
  const int wr   = (wave >> 1) * 32;
  const int wc   = (wave & 1) * 64;
  const int quad = lane >> 4;
  const int l15  = lane & 15;

  int bxn = blockIdx.x, byn = blockIdx.y;
  if (gridDim.x == 4 && gridDim.y == 128) {
    const int id2 = blockIdx.y * 4 + blockIdx.x;
    const int xcd = id2 & 7, w = id2 >> 3;
    bxn = w & 3;
    byn = xcd * 16 + (w >> 2);
  }
  const int bm = byn * 64;
  const int bn = bxn * 128;
  const int k0 = blockIdx.z * Kchunk;

  // A: 512 chunks (64 rows x 128B); B: 1024 chunks (128 rows x 128B)
  const int a0 = tid, a1 = tid + 256;
  const int ar0 = a0 >> 3, ac0 = ((a0 & 7) ^ (ar0 & 7)) << 4;
  const int ar1 = a1 >> 3, ac1 = ((a1 & 7) ^ (ar1 & 7)) << 4;
  const int b0 = tid, b1 = tid + 256, b2 = tid + 512, b3 = tid + 768;
  const int br0 = b0 >> 3, bc0 = ((b0 & 7) ^ (br0 & 7)) << 4;
  const int br1 = b1 >> 3, bc1 = ((b1 & 7) ^ (br1 & 7)) << 4;
  const int br2 = b2 >> 3, bc2 = ((b2 & 7) ^ (br2 & 7)) << 4;
  const int br3 = b3 >> 3, bc3 = ((b3 & 7) ^ (br3 & 7)) << 4;

  auto stage = [&](int kt, int b) {
    __builtin_amdgcn_global_load_lds(
        (const GLOBAL_AS void*)(P + (size_t)(bm + ar0) * 8192 + kt + ac0),
        (LDS_AS void*)(&As[b][a0 * 16]), 16, 0, 0);
    __builtin_amdgcn_global_load_lds(
        (const GLOBAL_AS void*)(P + (size_t)(bm + ar1) * 8192 + kt + ac1),
        (LDS_AS void*)(&As[b][a1 * 16]), 16, 0, 0);
    __builtin_amdgcn_global_load_lds(
        (const GLOBAL_AS void*)(Bt + (size_t)(bn + br0) * 8192 + kt + bc0),
        (LDS_AS void*)(&Bs[b][b0 * 16]), 16, 0, 0);
    __builtin_amdgcn_global_load_lds(
        (const GLOBAL_AS void*)(Bt + (size_t)(bn + br1) * 8192 + kt + bc1),
        (LDS_AS void*)(&Bs[b][b1 * 16]), 16, 0, 0);
    __builtin_amdgcn_global_load_lds(
        (const GLOBAL_AS void*)(Bt + (size_t)(bn + br2) * 8192 + kt + bc2),
        (LDS_AS void*)(&Bs[b][b2 * 16]), 16, 0, 0);
    __builtin_amdgcn_global_load_lds(
        (const GLOBAL_AS void*)(Bt + (size_t)(bn + br3) * 8192 + kt + bc3),
        (LDS_AS void*)(&Bs[b][b3 * 16]), 16, 0, 0);
  };

  floatx4 acc[2][4];
#pragma unroll
  for (int i = 0; i < 2; ++i)
#pragma unroll
    for (int j = 0; j < 4; ++j)
      acc[i][j] = (floatx4){0.f, 0.f, 0.f, 0.f};

  stage(k0, 0);
  const int nIter = Kchunk >> 7;
  for (int it = 0; it < nIter; ++it) {
    const int b = it & 1;
    wait_vm0();
    __syncthreads();
    if (it + 1 < nIter) stage(k0 + ((it + 1) << 7), b ^ 1);

    const int8v af0 = load_frag32(As[b], wr + l15, quad);
    const int8v af1 = load_frag32(As[b], wr + 16 + l15, quad);
#pragma unroll
    for (int j = 0; j < 4; ++j) {
      const int8v bf = load_frag32(Bs[b], wc + j * 16 + l15, quad);
      acc[0][j] = mx_mfma(af0, bf, acc[0][j]);
      acc[1][j] = mx_mfma(af1, bf, acc[1][j]);
    }
  }

  // epilogue: atomic accumulate v/l into out (pre-filled with H)
#pragma unroll
  for (int i = 0; i < 2; ++i) {
    const int rl = bm + wr + i * 16 + quad * 4;
#pragma unroll
    for (int r = 0; r < 4; ++r) {
      const int grow = row0 + rl + r;
      const float inv = 1.f / lvec[grow];
#pragma unroll
      for (int j = 0; j < 4; ++j) {
        const int col = bn + wc + j * 16 + l15;
        atomicAdd(&out[(size_t)grow * 512 + col], acc[i][j][r] * inv);
      }
    }
  }
}

// ---------------------------------------------------------------------------
extern "C" void kernel_launch(void* const* d_in, const int* in_sizes, int n_in,
                              void* d_out, int out_size, void* d_ws, size_t ws_size,
                              hipStream_t stream) {
  const float* H  = (const float*)d_in[0];
  const float* Wq = (const float*)d_in[1];
  const float* bq = (const float*)d_in[2];
  const float* Wk = (const float*)d_in[3];
  const float* bk = (const float*)d_in[4];
  float* out = (float*)d_out;

  const int N = 8192, D = 512;

  char* ws = (char*)d_ws;
  size_t off = 0;
  auto alloc = [&](size_t bytes) { char* p = ws + off; off += bytes; return p; };
  unsigned short* Hb   = (unsigned short*)alloc((size_t)N * D * 2);       // 8 MB
  unsigned char*  HbT8 = (unsigned char*)alloc((size_t)D * N);            // 4.2 MB
  unsigned char*  QK8  = (unsigned char*)alloc((size_t)N * 2 * D);        // 8.4 MB
  unsigned short* BqkT = (unsigned short*)alloc((size_t)2 * D * D * 2);   // 1 MB
  float* bqk = (float*)alloc((size_t)2 * D * 4);
  float* l   = (float*)alloc((size_t)N * 4);
  const size_t base = off;
  unsigned char* P8 = (unsigned char*)(ws + base);

  const size_t pBytes = (size_t)N * N;                   // 67 MB (fp8)
  const size_t avail = (ws_size > base) ? (ws_size - base) : 0;
  const bool fullP = (avail >= pBytes);

  // --- prep (also prefills out = H for pv8's atomic accumulation) ---
  hipMemsetAsync(l, 0, (size_t)N * 4, stream);
  transpose_h_kernel<<<dim3(D / 64, N / 64), 256, 0, stream>>>(H, HbT8, Hb, out, N, D);
  transpose_w2_kernel<<<dim3(D / 64, D / 64, 2), 256, 0, stream>>>(Wq, Wk, BqkT, D);
  pack_bias_kernel<<<dim3(4), 256, 0, stream>>>(bq, bk, bqk);

  // --- merged Q|K projection -> fp8: QK8[8192][1024] (sigma1 cols) ---
  gemm_proj<<<dim3(2 * D / 128, N / 128), 256, 0, stream>>>(
      Hb, BqkT, 2 * D, D, bqk, QK8);

  if (fullP) {
    // scores: P8 = fp8(exp(diag0(Q K^T)*scale)), fused row-sums into l
    gemm_qk8<<<dim3(N / 256, N / 256), 512, 0, stream>>>(
        QK8, QK8 + D, N, D, 2 * D, 2 * D, l, 0, P8);
    // PV split-K over 2 z-slices, atomic accumulate into out (+H prefill)
    gemm_pv8<<<dim3(D / 128, N / 64, 2), 256, 0, stream>>>(
        P8, HbT8, N / 2, l, 0, out);
  } else {
    // ws too small for full P8: chunk rows (atomic PV per chunk, z=1)
    int maxRows = (int)(avail / (size_t)N);
    maxRows &= ~255;
    if (maxRows < 256) maxRows = 256;
    for (int r0 = 0; r0 < N; r0 += maxRows) {
      int rows = N - r0;
      if (rows > maxRows) rows = maxRows;
      gemm_qk8<<<dim3(N / 256, rows / 256), 512, 0, stream>>>(
          QK8 + (size_t)r0 * 2 * D, QK8 + D, N, D, 2 * D, 2 * D, l, r0, P8);
      gemm_pv8<<<dim3(D / 128, rows / 64, 1), 256, 0, stream>>>(
          P8, HbT8, N, l, r0, out);
    }
  }
}

// Round 7
// 277.231 us; speedup vs baseline: 1.0061x; 1.0061x over previous
//
#include <hip/hip_runtime.h>
#include <cstdint>
#include <cstddef>

#define GLOBAL_AS __attribute__((address_space(1)))
#define LDS_AS __attribute__((address_space(3)))

typedef __attribute__((ext_vector_type(8))) short short8;
typedef __attribute__((ext_vector_type(4))) float floatx4;
typedef __attribute__((ext_vector_type(2))) long long2v;   // 16B LDS read
typedef __attribute__((ext_vector_type(4))) int int4v;
typedef __attribute__((ext_vector_type(8))) int int8v;

#if defined(__has_builtin)
#if __has_builtin(__builtin_amdgcn_cvt_pk_fp8_f32)
#define HAVE_HW_FP8 1
#endif
#endif

static __device__ __forceinline__ unsigned short f2bf(float f) {
  uint32_t u = __builtin_bit_cast(uint32_t, f);
  u += 0x7fffu + ((u >> 16) & 1u);
  return (unsigned short)(u >> 16);
}

// OCP e4m3 encode (RNE, saturate to 448)
static __device__ __forceinline__ unsigned char f2fp8(float f) {
#ifdef HAVE_HW_FP8
  float c = fminf(fmaxf(f, -448.f), 448.f);
  return (unsigned char)(__builtin_amdgcn_cvt_pk_fp8_f32(c, 0.f, 0, false) & 0xff);
#else
  unsigned char s = 0;
  if (f < 0.f) { s = 0x80; f = -f; }
  if (f >= 448.f) return s | 0x7e;
  if (f < 0.015625f) { int r = (int)(f * 512.f + 0.5f); return s | (unsigned char)r; }
  uint32_t u = __builtin_bit_cast(uint32_t, f);
  int e = (int)((u >> 23) & 0xff) - 127;
  uint32_t keep = (u >> 20) & 7, rest = u & 0xfffffu;
  if (rest > 0x80000u || (rest == 0x80000u && (keep & 1))) ++keep;
  if (keep == 8) { keep = 0; ++e; }
  if (e > 8) return s | 0x7e;
  return s | (unsigned char)(((e + 7) << 3) | keep);
#endif
}

// pack 4 fp8 bytes (cols l15+{0,16,32,48}) into one dword, bytes in j order
static __device__ __forceinline__ uint32_t pack4fp8(const float e[4]) {
#ifdef HAVE_HW_FP8
  const uint32_t p01 = (uint32_t)__builtin_amdgcn_cvt_pk_fp8_f32(e[0], e[1], 0, false);
  const uint32_t p23 = (uint32_t)__builtin_amdgcn_cvt_pk_fp8_f32(e[2], e[3], 0, false);
  return (p01 & 0xffffu) | (p23 << 16);
#else
  return (uint32_t)f2fp8(e[0]) | ((uint32_t)f2fp8(e[1]) << 8) |
         ((uint32_t)f2fp8(e[2]) << 16) | ((uint32_t)f2fp8(e[3]) << 24);
#endif
}

// ---------------------------------------------------------------------------
// FP8 STORAGE PERMUTATION (both-sides trick): every fp8 tensor stores, within
// each 64-byte column group, original col c at byte s = 4*(c&15) + (c>>4)
// (16x16 MFMA C-fragment-native). Consumers apply the same k-permutation to
// A and B -> dot products unchanged.
// ---------------------------------------------------------------------------

static __device__ __forceinline__ void wait_vm0() {
  __builtin_amdgcn_s_waitcnt(0x0f70);  // vmcnt(0)
}

// ---------------------------------------------------------------------------
// MX helpers (pv8): identity scale E8M0=127 (=1.0) -> arithmetic identical
// to non-scaled e4m3. B staged in LDS with row-chunk swizzle (conflict-free);
// A (P8) read DIRECT global->reg (T14): same bytes the LDS path resolved to.
// ---------------------------------------------------------------------------
static __device__ __forceinline__ int8v load_frag32(const unsigned char* base, int row, int quad) {
  const int h = row & 7;
  const int c0 = (2 * quad) ^ h;
  const int c1 = (2 * quad + 1) ^ h;
  const int4v lo = *(const int4v*)(base + row * 128 + c0 * 16);
  const int4v hi = *(const int4v*)(base + row * 128 + c1 * 16);
  int8v r;
  r[0] = lo[0]; r[1] = lo[1]; r[2] = lo[2]; r[3] = lo[3];
  r[4] = hi[0]; r[5] = hi[1]; r[6] = hi[2]; r[7] = hi[3];
  return r;
}

static __device__ __forceinline__ int8v cat8(int4v lo, int4v hi) {
  int8v r;
  r[0] = lo[0]; r[1] = lo[1]; r[2] = lo[2]; r[3] = lo[3];
  r[4] = hi[0]; r[5] = hi[1]; r[6] = hi[2]; r[7] = hi[3];
  return r;
}

static __device__ __forceinline__ floatx4 mx_mfma(int8v a, int8v b, floatx4 c) {
  return __builtin_amdgcn_mfma_scale_f32_16x16x128_f8f6f4(a, b, c, 0, 0, 0, 0x7f, 0, 0x7f);
}

// ---------------------------------------------------------------------------
// Transpose H: fp32 [R][C] -> HbT8 fp8 [C][R] (R permuted sigma1 within
// 64-groups to match P8's col permutation), plus straight bf16 copy [R][C],
// plus residual prefill out = H (pv8 atomically accumulates on top).
// ---------------------------------------------------------------------------
__global__ __launch_bounds__(256) void transpose_h_kernel(
    const float* __restrict__ in, unsigned char* __restrict__ outT8,
    unsigned short* __restrict__ outN, float* __restrict__ outF,
    int R, int C) {
  __shared__ float t[64][65];
  const int bc = blockIdx.x * 64;
  const int br = blockIdx.y * 64;
  const int tc = threadIdx.x & 63;
  const int tr = threadIdx.x >> 6;
  for (int r = tr; r < 64; r += 4) {
    const float v = in[(size_t)(br + r) * C + bc + tc];
    t[r][tc] = v;
    outN[(size_t)(br + r) * C + bc + tc] = f2bf(v);
    outF[(size_t)(br + r) * C + bc + tc] = v;   // residual prefill
  }
  __syncthreads();
  const int tperm = 4 * (tc & 15) + (tc >> 4);   // sigma1: match P8 col perm
  for (int r = tr; r < 64; r += 4)
    outT8[(size_t)(bc + r) * R + br + tperm] = f2fp8(t[tc][r]);
}

// Transpose both weights: fp32 [D][D] -> bf16 [D][D]^T, z selects Wq/Wk
__global__ __launch_bounds__(256) void transpose_w2_kernel(
    const float* __restrict__ Wq, const float* __restrict__ Wk,
    unsigned short* __restrict__ outT, int Dd) {
  const float* in = blockIdx.z ? Wk : Wq;
  unsigned short* out = outT + (size_t)blockIdx.z * Dd * Dd;
  __shared__ float t[64][65];
  const int bc = blockIdx.x * 64;
  const int br = blockIdx.y * 64;
  const int tc = threadIdx.x & 63;
  const int tr = threadIdx.x >> 6;
  for (int r = tr; r < 64; r += 4)
    t[r][tc] = in[(size_t)(br + r) * Dd + bc + tc];
  __syncthreads();
  for (int r = tr; r < 64; r += 4)
    out[(size_t)(bc + r) * Dd + br + tc] = f2bf(t[tc][r]);
}

__global__ __launch_bounds__(256) void pack_bias_kernel(
    const float* __restrict__ bq, const float* __restrict__ bk,
    float* __restrict__ bqk) {
  int i = blockIdx.x * 256 + threadIdx.x;
  bqk[i] = (i < 512) ? bq[i] : bk[i - 512];
}

// ---------------------------------------------------------------------------
// Projection GEMM (bf16 x bf16 -> fp8): QK8[m][p(n)] = fp8(A[m][k]*Bt[n][k]+b[n])
// 128x128 tile, BK=32, double-buffered one-barrier K-loop. Output sigma1.
// ---------------------------------------------------------------------------
__global__ __launch_bounds__(256, 4) void gemm_proj(
    const unsigned short* __restrict__ A,    // Hb [8192][512] bf16
    const unsigned short* __restrict__ Bt,   // BqkT [1024][512] bf16
    int Ncols, int K,
    const float* __restrict__ bias,
    unsigned char* __restrict__ C8)          // QK8 [8192][1024] fp8 (sigma1 cols)
{
  __shared__ unsigned short As[2][128 * 32];
  __shared__ unsigned short Bs[2][128 * 32];

  const int tid  = threadIdx.x;
  const int lane = tid & 63;
  const int wave = tid >> 6;
  const int wr   = (wave >> 1) * 64;
  const int wc   = (wave & 1) * 64;
  const int quad = lane >> 4;
  const int l15  = lane & 15;
  const int bm   = blockIdx.y * 128;
  const int bn   = blockIdx.x * 128;

  const int c0 = tid, c1 = tid + 256;
  const int r0a = c0 >> 2, k0a = (((c0 & 3) ^ ((c0 >> 3) & 3)) << 3);
  const int r1a = c1 >> 2, k1a = (((c1 & 3) ^ ((c1 >> 3) & 3)) << 3);

  auto stage = [&](int kt, int b) {
    __builtin_amdgcn_global_load_lds(
        (const GLOBAL_AS void*)(A + (size_t)(bm + r0a) * K + kt + k0a),
        (LDS_AS void*)(&As[b][c0 * 8]), 16, 0, 0);
    __builtin_amdgcn_global_load_lds(
        (const GLOBAL_AS void*)(A + (size_t)(bm + r1a) * K + kt + k1a),
        (LDS_AS void*)(&As[b][c1 * 8]), 16, 0, 0);
    __builtin_amdgcn_global_load_lds(
        (const GLOBAL_AS void*)(Bt + (size_t)(bn + r0a) * K + kt + k0a),
        (LDS_AS void*)(&Bs[b][c0 * 8]), 16, 0, 0);
    __builtin_amdgcn_global_load_lds(
        (const GLOBAL_AS void*)(Bt + (size_t)(bn + r1a) * K + kt + k1a),
        (LDS_AS void*)(&Bs[b][c1 * 8]), 16, 0, 0);
  };

  floatx4 acc[4][4];
#pragma unroll
  for (int i = 0; i < 4; ++i)
#pragma unroll
    for (int j = 0; j < 4; ++j)
      acc[i][j] = (floatx4){0.f, 0.f, 0.f, 0.f};

  stage(0, 0);
  const int swq = quad ^ ((l15 >> 1) & 3);   // un-swizzle: orig chunk `quad`
  const int nIter = K >> 5;
  for (int it = 0; it < nIter; ++it) {
    const int b = it & 1;
    wait_vm0();
    __syncthreads();
    if (it + 1 < nIter) stage((it + 1) << 5, b ^ 1);

    short8 af[4], bfr[4];
#pragma unroll
    for (int i = 0; i < 4; ++i)
      af[i] = *(const short8*)(&As[b][(wr + i * 16 + l15) * 32 + swq * 8]);
#pragma unroll
    for (int j = 0; j < 4; ++j)
      bfr[j] = *(const short8*)(&Bs[b][(wc + j * 16 + l15) * 32 + swq * 8]);
#pragma unroll
    for (int i = 0; i < 4; ++i)
#pragma unroll
      for (int j = 0; j < 4; ++j)
        acc[i][j] = __builtin_amdgcn_mfma_f32_16x16x32_bf16(af[i], bfr[j], acc[i][j], 0, 0, 0);
  }

  // epilogue — C/D layout: col = lane&15, row = quad*4 + reg. sigma1 store.
#pragma unroll
  for (int i = 0; i < 4; ++i) {
    const int rl = bm + wr + i * 16 + quad * 4;
#pragma unroll
    for (int r = 0; r < 4; ++r) {
      const int row = rl + r;
      float e[4];
#pragma unroll
      for (int j = 0; j < 4; ++j)
        e[j] = acc[i][j][r] + bias[bn + wc + j * 16 + l15];
      const uint32_t d = pack4fp8(e);
      *(uint32_t*)(C8 + (size_t)row * Ncols + bn + wc + 4 * l15) = d;
    }
  }
}

// ---------------------------------------------------------------------------
// Scores GEMM fp8 x fp8 (REVERTED to verified round-4/5 structure):
// 128x128 tile, BK=64, 256 threads, acc[4][4], double-buffered one-barrier
// loop, (256,4). XCD region swizzle. Output P8 fragment-native sigma1.
// ---------------------------------------------------------------------------
__global__ __launch_bounds__(256, 4) void gemm_qk8(
    const unsigned char* __restrict__ A,     // Q8 rows [.][lda] fp8
    const unsigned char* __restrict__ Bt,    // K8 [8192][ldb] fp8
    int Ncols, int K, int lda, int ldb,
    float* __restrict__ lsum,
    int row0,
    unsigned char* __restrict__ P8)
{
  __shared__ unsigned char As[2][128 * 64];   // 8 KiB x2
  __shared__ unsigned char Bs[2][128 * 64];   // 8 KiB x2

  const int tid  = threadIdx.x;
  const int lane = tid & 63;
  const int wave = tid >> 6;
  const int wr   = (wave >> 1) * 64;
  const int wc   = (wave & 1) * 64;
  const int quad = lane >> 4;
  const int l15  = lane & 15;

  int bxn = blockIdx.x, byn = blockIdx.y;
  if (gridDim.x == 64 && gridDim.y == 64) {
    const int id = blockIdx.y * 64 + blockIdx.x;
    const int r = id & 7, w = id >> 3;
    bxn = (r & 3) * 16 + (w & 15);
    byn = (r >> 2) * 32 + (w >> 4);
  }
  const int bm = byn * 128;
  const int bn = bxn * 128;

  // staging: 512 chunks of 16B cover 128 rows x 64B; chunk swizzled by row
  const int c0 = tid, c1 = tid + 256;
  const int r0a = c0 >> 2, k0a = (((c0 & 3) ^ ((c0 >> 3) & 3)) << 4);
  const int r1a = c1 >> 2, k1a = (((c1 & 3) ^ ((c1 >> 3) & 3)) << 4);

  auto stage = [&](int kt, int b) {
    __builtin_amdgcn_global_load_lds(
        (const GLOBAL_AS void*)(A + (size_t)(bm + r0a) * lda + kt + k0a),
        (LDS_AS void*)(&As[b][c0 * 16]), 16, 0, 0);
    __builtin_amdgcn_global_load_lds(
        (const GLOBAL_AS void*)(A + (size_t)(bm + r1a) * lda + kt + k1a),
        (LDS_AS void*)(&As[b][c1 * 16]), 16, 0, 0);
    __builtin_amdgcn_global_load_lds(
        (const GLOBAL_AS void*)(Bt + (size_t)(bn + r0a) * ldb + kt + k0a),
        (LDS_AS void*)(&Bs[b][c0 * 16]), 16, 0, 0);
    __builtin_amdgcn_global_load_lds(
        (const GLOBAL_AS void*)(Bt + (size_t)(bn + r1a) * ldb + kt + k1a),
        (LDS_AS void*)(&Bs[b][c1 * 16]), 16, 0, 0);
  };

  floatx4 acc[4][4];
#pragma unroll
  for (int i = 0; i < 4; ++i)
#pragma unroll
    for (int j = 0; j < 4; ++j)
      acc[i][j] = (floatx4){0.f, 0.f, 0.f, 0.f};

  stage(0, 0);
  const int swq = quad ^ ((l15 >> 1) & 3);   // un-swizzle: orig chunk `quad`
  const int nIter = K >> 6;
  for (int it = 0; it < nIter; ++it) {
    const int b = it & 1;
    wait_vm0();
    __syncthreads();
    if (it + 1 < nIter) stage((it + 1) << 6, b ^ 1);

    long2v af[4], bfr[4];
#pragma unroll
    for (int i = 0; i < 4; ++i)
      af[i] = *(const long2v*)(&As[b][(wr + i * 16 + l15) * 64 + swq * 16]);
#pragma unroll
    for (int j = 0; j < 4; ++j)
      bfr[j] = *(const long2v*)(&Bs[b][(wc + j * 16 + l15) * 64 + swq * 16]);
#pragma unroll
    for (int i = 0; i < 4; ++i)
#pragma unroll
      for (int j = 0; j < 4; ++j) {
        acc[i][j] = __builtin_amdgcn_mfma_f32_16x16x32_fp8_fp8(af[i].x, bfr[j].x, acc[i][j], 0, 0, 0);
        acc[i][j] = __builtin_amdgcn_mfma_f32_16x16x32_fp8_fp8(af[i].y, bfr[j].y, acc[i][j], 0, 0, 0);
      }
  }

  const float scale = 0.044194173824159216f;  // 1/sqrt(512)
#pragma unroll
  for (int i = 0; i < 4; ++i) {
    const int rl = bm + wr + i * 16 + quad * 4;
#pragma unroll
    for (int r = 0; r < 4; ++r) {
      const int row = rl + r;
      float e4[4];
#pragma unroll
      for (int j = 0; j < 4; ++j) {
        const int col = bn + wc + j * 16 + l15;
        const float lg = ((row0 + row) == col) ? 0.f : acc[i][j][r] * scale;
        e4[j] = fminf(__expf(lg), 448.f);
      }
      // row-sum from fp32 values (fp8 num/denom inconsistency ~0.004% on l)
      float rsum = (e4[0] + e4[1]) + (e4[2] + e4[3]);
      const uint32_t d = pack4fp8(e4);   // fragment-native store, no gather
      *(uint32_t*)(P8 + (size_t)row * Ncols + bn + wc + 4 * l15) = d;
      rsum += __shfl_xor(rsum, 1);
      rsum += __shfl_xor(rsum, 2);
      rsum += __shfl_xor(rsum, 4);
      rsum += __shfl_xor(rsum, 8);
      if (l15 == 0) atomicAdd(&lsum[row0 + row], rsum);
    }
  }
}

// ---------------------------------------------------------------------------
// PV GEMM, MX fp8: out[m][n] += (sum_k P8[m][k]*HbT8[n][k]) / l[m].
// A (P8) is loaded DIRECT global->reg, double-buffered via 2x-unrolled loop
// (T14: issue next-iter loads with the staging, drain at the existing
// vmcnt(0)). Bytes identical to the old LDS path (chunks 2q,2q+1 of row
// wr+{l15,16+l15}) -> bit-identical math. B (HbT8, cross-wave reused) stays
// LDS-staged with the row-chunk swizzle. LDS 48->32 KB.
// XCD swizzle: 4 d-blocks sharing one 64-row P8 panel on one XCD's L2.
// ---------------------------------------------------------------------------
__global__ __launch_bounds__(256, 3) void gemm_pv8(
    const unsigned char* __restrict__ P,     // [rows][8192] fp8 (chunk base)
    const unsigned char* __restrict__ Bt,    // HbT8 [512][8192] fp8
    int Kchunk,
    const float* __restrict__ lvec,
    int row0,
    float* __restrict__ out)
{
  __shared__ unsigned char Bs[2][128 * 128];  // 16 KiB x2  (B only)

  const int tid  = threadIdx.x;
  const int lane = tid & 63;
  const int wave = tid >> 6;
  const int wr   = (wave >> 1) * 32;
  const int wc   = (wave & 1) * 64;
  const int quad = lane >> 4;
  const int l15  = lane & 15;

  int bxn = blockIdx.x, byn = blockIdx.y;
  if (gridDim.x == 4 && gridDim.y == 128) {
    const int id2 = blockIdx.y * 4 + blockIdx.x;
    const int xcd = id2 & 7, w = id2 >> 3;
    bxn = w & 3;
    byn = xcd * 16 + (w >> 2);
  }
  const int bm = byn * 64;
  const int bn = bxn * 128;
  const int k0 = blockIdx.z * Kchunk;

  // B staging: 1024 chunks (128 rows x 128B), row-chunk swizzle
  const int b0 = tid, b1 = tid + 256, b2 = tid + 512, b3 = tid + 768;
  const int br0 = b0 >> 3, bc0 = ((b0 & 7) ^ (br0 & 7)) << 4;
  const int br1 = b1 >> 3, bc1 = ((b1 & 7) ^ (br1 & 7)) << 4;
  const int br2 = b2 >> 3, bc2 = ((b2 & 7) ^ (br2 & 7)) << 4;
  const int br3 = b3 >> 3, bc3 = ((b3 & 7) ^ (br3 & 7)) << 4;

  auto stageB = [&](int kt, int b) {
    __builtin_amdgcn_global_load_lds(
        (const GLOBAL_AS void*)(Bt + (size_t)(bn + br0) * 8192 + kt + bc0),
        (LDS_AS void*)(&Bs[b][b0 * 16]), 16, 0, 0);
    __builtin_amdgcn_global_load_lds(
        (const GLOBAL_AS void*)(Bt + (size_t)(bn + br1) * 8192 + kt + bc1),
        (LDS_AS void*)(&Bs[b][b1 * 16]), 16, 0, 0);
    __builtin_amdgcn_global_load_lds(
        (const GLOBAL_AS void*)(Bt + (size_t)(bn + br2) * 8192 + kt + bc2),
        (LDS_AS void*)(&Bs[b][b2 * 16]), 16, 0, 0);
    __builtin_amdgcn_global_load_lds(
        (const GLOBAL_AS void*)(Bt + (size_t)(bn + br3) * 8192 + kt + bc3),
        (LDS_AS void*)(&Bs[b][b3 * 16]), 16, 0, 0);
  };

  // A direct-to-reg pointers: row wr+l15 (af0) and wr+16+l15 (af1),
  // bytes [quad*32, quad*32+32) of each BK=128 step (un-swizzled order).
  const unsigned char* ap0 = P + (size_t)(bm + wr + l15) * 8192 + quad * 32;
  const unsigned char* ap1 = P + (size_t)(bm + wr + 16 + l15) * 8192 + quad * 32;

  floatx4 acc[2][4];
#pragma unroll
  for (int i = 0; i < 2; ++i)
#pragma unroll
    for (int j = 0; j < 4; ++j)
      acc[i][j] = (floatx4){0.f, 0.f, 0.f, 0.f};

  // ping-pong A register sets (no dynamic indexing, no reg moves)
  int4v xa0lo, xa0hi, xa1lo, xa1hi;   // set X
  int4v ya0lo, ya0hi, ya1lo, ya1hi;   // set Y

  stageB(k0, 0);
  xa0lo = *(const int4v*)(ap0 + k0);
  xa0hi = *(const int4v*)(ap0 + k0 + 16);
  xa1lo = *(const int4v*)(ap1 + k0);
  xa1hi = *(const int4v*)(ap1 + k0 + 16);

  const int nIter = Kchunk >> 7;      // 32 (z=2) or 64 (z=1): always even
  for (int it = 0; it < nIter; it += 2) {
    // ---- sub-iter even: uses set X, prefetches set Y ----
    {
      wait_vm0();
      __syncthreads();
      const int kn = k0 + ((it + 1) << 7);
      if (it + 1 < nIter) {
        stageB(kn, 1);
        ya0lo = *(const int4v*)(ap0 + kn);
        ya0hi = *(const int4v*)(ap0 + kn + 16);
        ya1lo = *(const int4v*)(ap1 + kn);
        ya1hi = *(const int4v*)(ap1 + kn + 16);
      }
      const int8v af0 = cat8(xa0lo, xa0hi);
      const int8v af1 = cat8(xa1lo, xa1hi);
#pragma unroll
      for (int j = 0; j < 4; ++j) {
        const int8v bf = load_frag32(Bs[0], wc + j * 16 + l15, quad);
        acc[0][j] = mx_mfma(af0, bf, acc[0][j]);
        acc[1][j] = mx_mfma(af1, bf, acc[1][j]);
      }
    }
    // ---- sub-iter odd: uses set Y, prefetches set X ----
    if (it + 1 < nIter) {
      wait_vm0();
      __syncthreads();
      const int kn = k0 + ((it + 2) << 7);
      if (it + 2 < nIter) {
        stageB(kn, 0);
        xa0lo = *(const int4v*)(ap0 + kn);
        xa0hi = *(const int4v*)(ap0 + kn + 16);
        xa1lo = *(const int4v*)(ap1 + kn);
        xa1hi = *(const int4v*)(ap1 + kn + 16);
      }
      const int8v af0 = cat8(ya0lo, ya0hi);
      const int8v af1 = cat8(ya1lo, ya1hi);
#pragma unroll
      for (int j = 0; j < 4; ++j) {
        const int8v bf = load_frag32(Bs[1], wc + j * 16 + l15, quad);
        acc[0][j] = mx_mfma(af0, bf, acc[0][j]);
        acc[1][j] = mx_mfma(af1, bf, acc[1][j]);
      }
    }
  }

  // epilogue: atomic accumulate v/l into out (pre-filled with H)
#pragma unroll
  for (int i = 0; i < 2; ++i) {
    const int rl = bm + wr + i * 16 + quad * 4;
#pragma unroll
    for (int r = 0; r < 4; ++r) {
      const int grow = row0 + rl + r;
      const float inv = 1.f / lvec[grow];
#pragma unroll
      for (int j = 0; j < 4; ++j) {
        const int col = bn + wc + j * 16 + l15;
        atomicAdd(&out[(size_t)grow * 512 + col], acc[i][j][r] * inv);
      }
    }
  }
}

// ---------------------------------------------------------------------------
extern "C" void kernel_launch(void* const* d_in, const int* in_sizes, int n_in,
                              void* d_out, int out_size, void* d_ws, size_t ws_size,
                              hipStream_t stream) {
  const float* H  = (const float*)d_in[0];
  const float* Wq = (const float*)d_in[1];
  const float* bq = (const float*)d_in[2];
  const float* Wk = (const float*)d_in[3];
  const float* bk = (const float*)d_in[4];
  float* out = (float*)d_out;

  const int N = 8192, D = 512;

  char* ws = (char*)d_ws;
  size_t off = 0;
  auto alloc = [&](size_t bytes) { char* p = ws + off; off += bytes; return p; };
  unsigned short* Hb   = (unsigned short*)alloc((size_t)N * D * 2);       // 8 MB
  unsigned char*  HbT8 = (unsigned char*)alloc((size_t)D * N);            // 4.2 MB
  unsigned char*  QK8  = (unsigned char*)alloc((size_t)N * 2 * D);        // 8.4 MB
  unsigned short* BqkT = (unsigned short*)alloc((size_t)2 * D * D * 2);   // 1 MB
  float* bqk = (float*)alloc((size_t)2 * D * 4);
  float* l   = (float*)alloc((size_t)N * 4);
  const size_t base = off;
  unsigned char* P8 = (unsigned char*)(ws + base);

  const size_t pBytes = (size_t)N * N;                   // 67 MB (fp8)
  const size_t avail = (ws_size > base) ? (ws_size - base) : 0;
  const bool fullP = (avail >= pBytes);

  // --- prep (also prefills out = H for pv8's atomic accumulation) ---
  hipMemsetAsync(l, 0, (size_t)N * 4, stream);
  transpose_h_kernel<<<dim3(D / 64, N / 64), 256, 0, stream>>>(H, HbT8, Hb, out, N, D);
  transpose_w2_kernel<<<dim3(D / 64, D / 64, 2), 256, 0, stream>>>(Wq, Wk, BqkT, D);
  pack_bias_kernel<<<dim3(4), 256, 0, stream>>>(bq, bk, bqk);

  // --- merged Q|K projection -> fp8: QK8[8192][1024] (sigma1 cols) ---
  gemm_proj<<<dim3(2 * D / 128, N / 128), 256, 0, stream>>>(
      Hb, BqkT, 2 * D, D, bqk, QK8);

  if (fullP) {
    // scores: P8 = fp8(exp(diag0(Q K^T)*scale)), fused row-sums into l
    gemm_qk8<<<dim3(N / 128, N / 128), 256, 0, stream>>>(
        QK8, QK8 + D, N, D, 2 * D, 2 * D, l, 0, P8);
    // PV split-K over 2 z-slices, atomic accumulate into out (+H prefill)
    gemm_pv8<<<dim3(D / 128, N / 64, 2), 256, 0, stream>>>(
        P8, HbT8, N / 2, l, 0, out);
  } else {
    // ws too small for full P8: chunk rows (atomic PV per chunk, z=1)
    int maxRows = (int)(avail / (size_t)N);
    maxRows &= ~127;
    if (maxRows < 128) maxRows = 128;
    for (int r0 = 0; r0 < N; r0 += maxRows) {
      int rows = N - r0;
      if (rows > maxRows) rows = maxRows;
      gemm_qk8<<<dim3(N / 128, rows / 128), 256, 0, stream>>>(
          QK8 + (size_t)r0 * 2 * D, QK8 + D, N, D, 2 * D, 2 * D, l, r0, P8);
      gemm_pv8<<<dim3(D / 128, rows / 64, 1), 256, 0, stream>>>(
          P8, HbT8, N, l, r0, out);
    }
  }
}

// Round 8
// 252.292 us; speedup vs baseline: 1.1056x; 1.0989x over previous
//
#include <hip/hip_runtime.h>
#include <cstdint>
#include <cstddef>

#define GLOBAL_AS __attribute__((address_space(1)))
#define LDS_AS __attribute__((address_space(3)))

typedef __attribute__((ext_vector_type(8))) short short8;
typedef __attribute__((ext_vector_type(4))) float floatx4;
typedef __attribute__((ext_vector_type(2))) long long2v;   // 16B LDS read

#if defined(__has_builtin)
#if __has_builtin(__builtin_amdgcn_cvt_pk_fp8_f32)
#define HAVE_HW_FP8 1
#endif
#endif

static __device__ __forceinline__ unsigned short f2bf(float f) {
  uint32_t u = __builtin_bit_cast(uint32_t, f);
  u += 0x7fffu + ((u >> 16) & 1u);
  return (unsigned short)(u >> 16);
}

// OCP e4m3 encode (RNE, saturate to 448)
static __device__ __forceinline__ unsigned char f2fp8(float f) {
#ifdef HAVE_HW_FP8
  float c = fminf(fmaxf(f, -448.f), 448.f);
  return (unsigned char)(__builtin_amdgcn_cvt_pk_fp8_f32(c, 0.f, 0, false) & 0xff);
#else
  unsigned char s = 0;
  if (f < 0.f) { s = 0x80; f = -f; }
  if (f >= 448.f) return s | 0x7e;
  if (f < 0.015625f) { int r = (int)(f * 512.f + 0.5f); return s | (unsigned char)r; }
  uint32_t u = __builtin_bit_cast(uint32_t, f);
  int e = (int)((u >> 23) & 0xff) - 127;
  uint32_t keep = (u >> 20) & 7, rest = u & 0xfffffu;
  if (rest > 0x80000u || (rest == 0x80000u && (keep & 1))) ++keep;
  if (keep == 8) { keep = 0; ++e; }
  if (e > 8) return s | 0x7e;
  return s | (unsigned char)(((e + 7) << 3) | keep);
#endif
}

// pack 4 fp8 bytes (cols l15+{0,16,32,48}) into one dword, bytes in j order
static __device__ __forceinline__ uint32_t pack4fp8(const float e[4]) {
#ifdef HAVE_HW_FP8
  const uint32_t p01 = (uint32_t)__builtin_amdgcn_cvt_pk_fp8_f32(e[0], e[1], 0, false);
  const uint32_t p23 = (uint32_t)__builtin_amdgcn_cvt_pk_fp8_f32(e[2], e[3], 0, false);
  return (p01 & 0xffffu) | (p23 << 16);
#else
  return (uint32_t)f2fp8(e[0]) | ((uint32_t)f2fp8(e[1]) << 8) |
         ((uint32_t)f2fp8(e[2]) << 16) | ((uint32_t)f2fp8(e[3]) << 24);
#endif
}

// ---------------------------------------------------------------------------
// FP8 STORAGE PERMUTATION (both-sides trick): every fp8 tensor stores, within
// each 64-byte column group, original col c at byte s = 4*(c&15) + (c>>4)
// (16x16 MFMA C-fragment-native). Consumers apply the same k-permutation to
// A and B -> dot products unchanged.
// ---------------------------------------------------------------------------

static __device__ __forceinline__ void wait_vm0() {
  __builtin_amdgcn_s_waitcnt(0x0f70);  // vmcnt(0)
}

// ---------------------------------------------------------------------------
// Transpose H: fp32 [R][C] -> HbT8 fp8 [C][R] (R permuted sigma1 within
// 64-groups to match P8's col permutation), plus straight bf16 copy [R][C]
// ---------------------------------------------------------------------------
__global__ __launch_bounds__(256) void transpose_h_kernel(
    const float* __restrict__ in, unsigned char* __restrict__ outT8,
    unsigned short* __restrict__ outN, int R, int C) {
  __shared__ float t[64][65];
  const int bc = blockIdx.x * 64;
  const int br = blockIdx.y * 64;
  const int tc = threadIdx.x & 63;
  const int tr = threadIdx.x >> 6;
  for (int r = tr; r < 64; r += 4) {
    const float v = in[(size_t)(br + r) * C + bc + tc];
    t[r][tc] = v;
    outN[(size_t)(br + r) * C + bc + tc] = f2bf(v);
  }
  __syncthreads();
  const int tperm = 4 * (tc & 15) + (tc >> 4);   // sigma1: match P8 col perm
  for (int r = tr; r < 64; r += 4)
    outT8[(size_t)(bc + r) * R + br + tperm] = f2fp8(t[tc][r]);
}

// Transpose both weights: fp32 [D][D] -> bf16 [D][D]^T, z selects Wq/Wk
__global__ __launch_bounds__(256) void transpose_w2_kernel(
    const float* __restrict__ Wq, const float* __restrict__ Wk,
    unsigned short* __restrict__ outT, int Dd) {
  const float* in = blockIdx.z ? Wk : Wq;
  unsigned short* out = outT + (size_t)blockIdx.z * Dd * Dd;
  __shared__ float t[64][65];
  const int bc = blockIdx.x * 64;
  const int br = blockIdx.y * 64;
  const int tc = threadIdx.x & 63;
  const int tr = threadIdx.x >> 6;
  for (int r = tr; r < 64; r += 4)
    t[r][tc] = in[(size_t)(br + r) * Dd + bc + tc];
  __syncthreads();
  for (int r = tr; r < 64; r += 4)
    out[(size_t)(bc + r) * Dd + br + tc] = f2bf(t[tc][r]);
}

__global__ __launch_bounds__(256) void pack_bias_kernel(
    const float* __restrict__ bq, const float* __restrict__ bk,
    float* __restrict__ bqk) {
  int i = blockIdx.x * 256 + threadIdx.x;
  bqk[i] = (i < 512) ? bq[i] : bk[i - 512];
}

// ---------------------------------------------------------------------------
// Projection GEMM (bf16 x bf16 -> fp8): QK8[m][p(n)] = fp8(A[m][k]*Bt[n][k]+b[n])
// 128x128 tile, BK=32, double-buffered one-barrier K-loop. Output sigma1.
// ---------------------------------------------------------------------------
__global__ __launch_bounds__(256, 4) void gemm_proj(
    const unsigned short* __restrict__ A,    // Hb [8192][512] bf16
    const unsigned short* __restrict__ Bt,   // BqkT [1024][512] bf16
    int Ncols, int K,
    const float* __restrict__ bias,
    unsigned char* __restrict__ C8)          // QK8 [8192][1024] fp8 (sigma1 cols)
{
  __shared__ unsigned short As[2][128 * 32];
  __shared__ unsigned short Bs[2][128 * 32];

  const int tid  = threadIdx.x;
  const int lane = tid & 63;
  const int wave = tid >> 6;
  const int wr   = (wave >> 1) * 64;
  const int wc   = (wave & 1) * 64;
  const int quad = lane >> 4;
  const int l15  = lane & 15;
  const int bm   = blockIdx.y * 128;
  const int bn   = blockIdx.x * 128;

  const int c0 = tid, c1 = tid + 256;
  const int r0a = c0 >> 2, k0a = (((c0 & 3) ^ ((c0 >> 3) & 3)) << 3);
  const int r1a = c1 >> 2, k1a = (((c1 & 3) ^ ((c1 >> 3) & 3)) << 3);

  auto stage = [&](int kt, int b) {
    __builtin_amdgcn_global_load_lds(
        (const GLOBAL_AS void*)(A + (size_t)(bm + r0a) * K + kt + k0a),
        (LDS_AS void*)(&As[b][c0 * 8]), 16, 0, 0);
    __builtin_amdgcn_global_load_lds(
        (const GLOBAL_AS void*)(A + (size_t)(bm + r1a) * K + kt + k1a),
        (LDS_AS void*)(&As[b][c1 * 8]), 16, 0, 0);
    __builtin_amdgcn_global_load_lds(
        (const GLOBAL_AS void*)(Bt + (size_t)(bn + r0a) * K + kt + k0a),
        (LDS_AS void*)(&Bs[b][c0 * 8]), 16, 0, 0);
    __builtin_amdgcn_global_load_lds(
        (const GLOBAL_AS void*)(Bt + (size_t)(bn + r1a) * K + kt + k1a),
        (LDS_AS void*)(&Bs[b][c1 * 8]), 16, 0, 0);
  };

  floatx4 acc[4][4];
#pragma unroll
  for (int i = 0; i < 4; ++i)
#pragma unroll
    for (int j = 0; j < 4; ++j)
      acc[i][j] = (floatx4){0.f, 0.f, 0.f, 0.f};

  stage(0, 0);
  const int swq = quad ^ ((l15 >> 1) & 3);   // un-swizzle: orig chunk `quad`
  const int nIter = K >> 5;
  for (int it = 0; it < nIter; ++it) {
    const int b = it & 1;
    wait_vm0();
    __syncthreads();
    if (it + 1 < nIter) stage((it + 1) << 5, b ^ 1);

    short8 af[4], bfr[4];
#pragma unroll
    for (int i = 0; i < 4; ++i)
      af[i] = *(const short8*)(&As[b][(wr + i * 16 + l15) * 32 + swq * 8]);
#pragma unroll
    for (int j = 0; j < 4; ++j)
      bfr[j] = *(const short8*)(&Bs[b][(wc + j * 16 + l15) * 32 + swq * 8]);
#pragma unroll
    for (int i = 0; i < 4; ++i)
#pragma unroll
      for (int j = 0; j < 4; ++j)
        acc[i][j] = __builtin_amdgcn_mfma_f32_16x16x32_bf16(af[i], bfr[j], acc[i][j], 0, 0, 0);
  }

  // epilogue — C/D layout: col = lane&15, row = quad*4 + reg. sigma1 store.
#pragma unroll
  for (int i = 0; i < 4; ++i) {
    const int rl = bm + wr + i * 16 + quad * 4;
#pragma unroll
    for (int r = 0; r < 4; ++r) {
      const int row = rl + r;
      float e[4];
#pragma unroll
      for (int j = 0; j < 4; ++j)
        e[j] = acc[i][j][r] + bias[bn + wc + j * 16 + l15];
      const uint32_t d = pack4fp8(e);
      *(uint32_t*)(C8 + (size_t)row * Ncols + bn + wc + 4 * l15) = d;
    }
  }
}

// ---------------------------------------------------------------------------
// Scores GEMM fp8 x fp8 (round-4 verified best): 128x128 tile, BK=64,
// 256 threads, acc[4][4], double-buffered one-barrier loop, (256,4).
// XCD region swizzle. Output P8 fragment-native sigma1.
// ---------------------------------------------------------------------------
__global__ __launch_bounds__(256, 4) void gemm_qk8(
    const unsigned char* __restrict__ A,     // Q8 rows [.][lda] fp8
    const unsigned char* __restrict__ Bt,    // K8 [8192][ldb] fp8
    int Ncols, int K, int lda, int ldb,
    float* __restrict__ lsum,
    int row0,
    unsigned char* __restrict__ P8)
{
  __shared__ unsigned char As[2][128 * 64];   // 8 KiB x2
  __shared__ unsigned char Bs[2][128 * 64];   // 8 KiB x2

  const int tid  = threadIdx.x;
  const int lane = tid & 63;
  const int wave = tid >> 6;
  const int wr   = (wave >> 1) * 64;
  const int wc   = (wave & 1) * 64;
  const int quad = lane >> 4;
  const int l15  = lane & 15;

  int bxn = blockIdx.x, byn = blockIdx.y;
  if (gridDim.x == 64 && gridDim.y == 64) {
    const int id = blockIdx.y * 64 + blockIdx.x;
    const int r = id & 7, w = id >> 3;
    bxn = (r & 3) * 16 + (w & 15);
    byn = (r >> 2) * 32 + (w >> 4);
  }
  const int bm = byn * 128;
  const int bn = bxn * 128;

  // staging: 512 chunks of 16B cover 128 rows x 64B; chunk swizzled by row
  const int c0 = tid, c1 = tid + 256;
  const int r0a = c0 >> 2, k0a = (((c0 & 3) ^ ((c0 >> 3) & 3)) << 4);
  const int r1a = c1 >> 2, k1a = (((c1 & 3) ^ ((c1 >> 3) & 3)) << 4);

  auto stage = [&](int kt, int b) {
    __builtin_amdgcn_global_load_lds(
        (const GLOBAL_AS void*)(A + (size_t)(bm + r0a) * lda + kt + k0a),
        (LDS_AS void*)(&As[b][c0 * 16]), 16, 0, 0);
    __builtin_amdgcn_global_load_lds(
        (const GLOBAL_AS void*)(A + (size_t)(bm + r1a) * lda + kt + k1a),
        (LDS_AS void*)(&As[b][c1 * 16]), 16, 0, 0);
    __builtin_amdgcn_global_load_lds(
        (const GLOBAL_AS void*)(Bt + (size_t)(bn + r0a) * ldb + kt + k0a),
        (LDS_AS void*)(&Bs[b][c0 * 16]), 16, 0, 0);
    __builtin_amdgcn_global_load_lds(
        (const GLOBAL_AS void*)(Bt + (size_t)(bn + r1a) * ldb + kt + k1a),
        (LDS_AS void*)(&Bs[b][c1 * 16]), 16, 0, 0);
  };

  floatx4 acc[4][4];
#pragma unroll
  for (int i = 0; i < 4; ++i)
#pragma unroll
    for (int j = 0; j < 4; ++j)
      acc[i][j] = (floatx4){0.f, 0.f, 0.f, 0.f};

  stage(0, 0);
  const int swq = quad ^ ((l15 >> 1) & 3);   // un-swizzle: orig chunk `quad`
  const int nIter = K >> 6;
  for (int it = 0; it < nIter; ++it) {
    const int b = it & 1;
    wait_vm0();
    __syncthreads();
    if (it + 1 < nIter) stage((it + 1) << 6, b ^ 1);

    long2v af[4], bfr[4];
#pragma unroll
    for (int i = 0; i < 4; ++i)
      af[i] = *(const long2v*)(&As[b][(wr + i * 16 + l15) * 64 + swq * 16]);
#pragma unroll
    for (int j = 0; j < 4; ++j)
      bfr[j] = *(const long2v*)(&Bs[b][(wc + j * 16 + l15) * 64 + swq * 16]);
#pragma unroll
    for (int i = 0; i < 4; ++i)
#pragma unroll
      for (int j = 0; j < 4; ++j) {
        acc[i][j] = __builtin_amdgcn_mfma_f32_16x16x32_fp8_fp8(af[i].x, bfr[j].x, acc[i][j], 0, 0, 0);
        acc[i][j] = __builtin_amdgcn_mfma_f32_16x16x32_fp8_fp8(af[i].y, bfr[j].y, acc[i][j], 0, 0, 0);
      }
  }

  const float scale = 0.044194173824159216f;  // 1/sqrt(512)
#pragma unroll
  for (int i = 0; i < 4; ++i) {
    const int rl = bm + wr + i * 16 + quad * 4;
#pragma unroll
    for (int r = 0; r < 4; ++r) {
      const int row = rl + r;
      float e4[4];
#pragma unroll
      for (int j = 0; j < 4; ++j) {
        const int col = bn + wc + j * 16 + l15;
        const float lg = ((row0 + row) == col) ? 0.f : acc[i][j][r] * scale;
        e4[j] = fminf(__expf(lg), 448.f);
      }
      // row-sum from fp32 values (fp8 num/denom inconsistency ~0.004% on l)
      float rsum = (e4[0] + e4[1]) + (e4[2] + e4[3]);
      const uint32_t d = pack4fp8(e4);   // fragment-native store, no gather
      *(uint32_t*)(P8 + (size_t)row * Ncols + bn + wc + 4 * l15) = d;
      rsum += __shfl_xor(rsum, 1);
      rsum += __shfl_xor(rsum, 2);
      rsum += __shfl_xor(rsum, 4);
      rsum += __shfl_xor(rsum, 8);
      if (l15 == 0) atomicAdd(&lsum[row0 + row], rsum);
    }
  }
}

// ---------------------------------------------------------------------------
// PV GEMM — qk8-clone structure: O[m][n] = sum_k P8[m][k]*HbT8[n][k].
// 64x128 tile, BK=64, plain fp8 16x16x32 (MX dropped: pv8 is latency-bound,
// not MFMA-bound), LDS = A 2x4KB + B 2x8KB = 24 KB -> up to 6 blocks/CU
// (was 48 KB / 3 blocks): doubled wave-level overlap to hide the per-iter
// vmcnt(0) drain of L3-latency P8 loads. Staging/read swizzle identical to
// qk8's verified formulas; k-dim sigma1-consistent on both operands.
// Split-K over z (parts + combine, round-4 measured-best reduction).
// XCD swizzle: 4 d-blocks sharing one 64-row P8 panel on one XCD's L2.
// ---------------------------------------------------------------------------
template <bool DIRECT>
__global__ __launch_bounds__(256, 4) void gemm_pv8(
    const unsigned char* __restrict__ P,     // [rows][8192] fp8 (chunk base)
    const unsigned char* __restrict__ Bt,    // HbT8 [512][8192] fp8
    int Kchunk,
    const float* __restrict__ lvec,
    const float* __restrict__ Hres,
    int row0,
    float* __restrict__ outp,
    size_t partStride)
{
  __shared__ unsigned char As[2][64 * 64];    // 4 KiB x2
  __shared__ unsigned char Bs[2][128 * 64];   // 8 KiB x2

  const int tid  = threadIdx.x;
  const int lane = tid & 63;
  const int wave = tid >> 6;
  const int wr   = (wave >> 1) * 32;
  const int wc   = (wave & 1) * 64;
  const int quad = lane >> 4;
  const int l15  = lane & 15;

  int bxn = blockIdx.x, byn = blockIdx.y;
  if (gridDim.x == 4 && gridDim.y == 128) {
    const int id2 = blockIdx.y * 4 + blockIdx.x;
    const int xcd = id2 & 7, w = id2 >> 3;
    bxn = w & 3;
    byn = xcd * 16 + (w >> 2);
  }
  const int bm = byn * 64;
  const int bn = bxn * 128;
  const int k0 = blockIdx.z * Kchunk;

  float* part = outp + (DIRECT ? 0 : (size_t)blockIdx.z * partStride);

  // A: 256 chunks of 16B (64 rows x 64B); B: 512 chunks (128 rows x 64B).
  // chunk swizzle s = (row>>1)&3, same formula as qk8.
  const int ca = tid;
  const int ar = ca >> 2, ak = (((ca & 3) ^ ((ca >> 3) & 3)) << 4);
  const int cb0 = tid, cb1 = tid + 256;
  const int br0 = cb0 >> 2, bk0 = (((cb0 & 3) ^ ((cb0 >> 3) & 3)) << 4);
  const int br1 = cb1 >> 2, bk1 = (((cb1 & 3) ^ ((cb1 >> 3) & 3)) << 4);

  auto stage = [&](int kt, int b) {
    __builtin_amdgcn_global_load_lds(
        (const GLOBAL_AS void*)(P + (size_t)(bm + ar) * 8192 + kt + ak),
        (LDS_AS void*)(&As[b][ca * 16]), 16, 0, 0);
    __builtin_amdgcn_global_load_lds(
        (const GLOBAL_AS void*)(Bt + (size_t)(bn + br0) * 8192 + kt + bk0),
        (LDS_AS void*)(&Bs[b][cb0 * 16]), 16, 0, 0);
    __builtin_amdgcn_global_load_lds(
        (const GLOBAL_AS void*)(Bt + (size_t)(bn + br1) * 8192 + kt + bk1),
        (LDS_AS void*)(&Bs[b][cb1 * 16]), 16, 0, 0);
  };

  floatx4 acc[2][4];
#pragma unroll
  for (int i = 0; i < 2; ++i)
#pragma unroll
    for (int j = 0; j < 4; ++j)
      acc[i][j] = (floatx4){0.f, 0.f, 0.f, 0.f};

  stage(k0, 0);
  const int swq = quad ^ ((l15 >> 1) & 3);   // un-swizzle: orig chunk `quad`
  const int nIter = Kchunk >> 6;
  for (int it = 0; it < nIter; ++it) {
    const int b = it & 1;
    wait_vm0();
    __syncthreads();
    if (it + 1 < nIter) stage(k0 + ((it + 1) << 6), b ^ 1);

    long2v af[2], bfr[4];
#pragma unroll
    for (int i = 0; i < 2; ++i)
      af[i] = *(const long2v*)(&As[b][(wr + i * 16 + l15) * 64 + swq * 16]);
#pragma unroll
    for (int j = 0; j < 4; ++j)
      bfr[j] = *(const long2v*)(&Bs[b][(wc + j * 16 + l15) * 64 + swq * 16]);
#pragma unroll
    for (int i = 0; i < 2; ++i)
#pragma unroll
      for (int j = 0; j < 4; ++j) {
        acc[i][j] = __builtin_amdgcn_mfma_f32_16x16x32_fp8_fp8(af[i].x, bfr[j].x, acc[i][j], 0, 0, 0);
        acc[i][j] = __builtin_amdgcn_mfma_f32_16x16x32_fp8_fp8(af[i].y, bfr[j].y, acc[i][j], 0, 0, 0);
      }
  }

#pragma unroll
  for (int i = 0; i < 2; ++i) {
    const int rl = bm + wr + i * 16 + quad * 4;
#pragma unroll
    for (int j = 0; j < 4; ++j) {
      const int col = bn + wc + j * 16 + l15;
#pragma unroll
      for (int r = 0; r < 4; ++r) {
        const int row = rl + r;
        const float v = acc[i][j][r];
        if (DIRECT) {
          const int grow = row0 + row;
          part[(size_t)grow * 512 + col] =
              v / lvec[grow] + Hres[(size_t)grow * 512 + col];
        } else {
          part[(size_t)row * 512 + col] = v;
        }
      }
    }
  }
}

// combine: out = (sum_s partial_s) / l[row] + H
__global__ __launch_bounds__(256) void combine_kernel(
    const float* __restrict__ parts, size_t partStride, int S,
    const float* __restrict__ lvec, const float* __restrict__ Hres,
    float* __restrict__ out, int n4) {
  int i = blockIdx.x * 256 + threadIdx.x;
  if (i >= n4) return;
  float4 a = ((const float4*)parts)[i];
  for (int s = 1; s < S; ++s) {
    const float4 b = ((const float4*)(parts + (size_t)s * partStride))[i];
    a.x += b.x; a.y += b.y; a.z += b.z; a.w += b.w;
  }
  const int row = i >> 7;
  const float inv = 1.f / lvec[row];
  const float4 h = ((const float4*)Hres)[i];
  float4 o;
  o.x = a.x * inv + h.x;
  o.y = a.y * inv + h.y;
  o.z = a.z * inv + h.z;
  o.w = a.w * inv + h.w;
  ((float4*)out)[i] = o;
}

// ---------------------------------------------------------------------------
extern "C" void kernel_launch(void* const* d_in, const int* in_sizes, int n_in,
                              void* d_out, int out_size, void* d_ws, size_t ws_size,
                              hipStream_t stream) {
  const float* H  = (const float*)d_in[0];
  const float* Wq = (const float*)d_in[1];
  const float* bq = (const float*)d_in[2];
  const float* Wk = (const float*)d_in[3];
  const float* bk = (const float*)d_in[4];
  float* out = (float*)d_out;

  const int N = 8192, D = 512;

  char* ws = (char*)d_ws;
  size_t off = 0;
  auto alloc = [&](size_t bytes) { char* p = ws + off; off += bytes; return p; };
  unsigned short* Hb   = (unsigned short*)alloc((size_t)N * D * 2);       // 8 MB
  unsigned char*  HbT8 = (unsigned char*)alloc((size_t)D * N);            // 4.2 MB
  unsigned char*  QK8  = (unsigned char*)alloc((size_t)N * 2 * D);        // 8.4 MB
  unsigned short* BqkT = (unsigned short*)alloc((size_t)2 * D * D * 2);   // 1 MB
  float* bqk = (float*)alloc((size_t)2 * D * 4);
  float* l   = (float*)alloc((size_t)N * 4);
  const size_t base = off;
  unsigned char* P8 = (unsigned char*)(ws + base);

  const size_t pBytes = (size_t)N * N;                   // 67 MB (fp8)
  const size_t partBytes = (size_t)N * D * 4;            // 16.8 MB each
  const size_t partStride = (size_t)N * D;               // floats
  const size_t avail = (ws_size > base) ? (ws_size - base) : 0;

  int S = 0;
  if (avail >= pBytes) {
    const size_t extra = avail - pBytes;
    S = (extra >= 2 * partBytes) ? 2 : 1;
  }
  float* parts = (float*)(ws + base + pBytes);

  // --- prep ---
  hipMemsetAsync(l, 0, (size_t)N * 4, stream);
  transpose_h_kernel<<<dim3(D / 64, N / 64), 256, 0, stream>>>(H, HbT8, Hb, N, D);
  transpose_w2_kernel<<<dim3(D / 64, D / 64, 2), 256, 0, stream>>>(Wq, Wk, BqkT, D);
  pack_bias_kernel<<<dim3(4), 256, 0, stream>>>(bq, bk, bqk);

  // --- merged Q|K projection -> fp8: QK8[8192][1024] (sigma1 cols) ---
  gemm_proj<<<dim3(2 * D / 128, N / 128), 256, 0, stream>>>(
      Hb, BqkT, 2 * D, D, bqk, QK8);

  if (S >= 1) {
    // scores: P8 = fp8(exp(diag0(Q K^T)*scale)), fused row-sums into l
    gemm_qk8<<<dim3(N / 128, N / 128), 256, 0, stream>>>(
        QK8, QK8 + D, N, D, 2 * D, 2 * D, l, 0, P8);
    if (S == 1) {
      gemm_pv8<true><<<dim3(D / 128, N / 64, 1), 256, 0, stream>>>(
          P8, HbT8, N, l, H, 0, out, 0);
    } else {
      gemm_pv8<false><<<dim3(D / 128, N / 64, S), 256, 0, stream>>>(
          P8, HbT8, N / S, nullptr, nullptr, 0, parts, partStride);
      combine_kernel<<<dim3((N * D / 4 + 255) / 256), 256, 0, stream>>>(
          parts, partStride, S, l, H, out, N * D / 4);
    }
  } else {
    // ws too small for full P8: chunk rows (direct PV per chunk)
    int maxRows = (int)(avail / (size_t)N);
    maxRows &= ~127;
    if (maxRows < 128) maxRows = 128;
    for (int r0 = 0; r0 < N; r0 += maxRows) {
      int rows = N - r0;
      if (rows > maxRows) rows = maxRows;
      gemm_qk8<<<dim3(N / 128, rows / 128), 256, 0, stream>>>(
          QK8 + (size_t)r0 * 2 * D, QK8 + D, N, D, 2 * D, 2 * D, l, r0, P8);
      gemm_pv8<true><<<dim3(D / 128, rows / 64, 1), 256, 0, stream>>>(
          P8, HbT8, N, l, H, r0, out, 0);
    }
  }
}